// Round 4
// baseline (4656.728 us; speedup 1.0000x reference)
//
#include <hip/hip_runtime.h>
#include <stdint.h>

typedef _Float16 half2v __attribute__((ext_vector_type(2)));

__device__ __forceinline__ float sigf(float x) {
    return __builtin_amdgcn_rcpf(1.0f + __expf(-x));
}
__device__ __forceinline__ float tanhf_fast(float x) {
    return 1.0f - 2.0f * __builtin_amdgcn_rcpf(1.0f + __expf(2.0f * x));
}
__device__ __forceinline__ uint32_t pk2(float a, float b) {
    uint16_t ua = __builtin_bit_cast(uint16_t, (_Float16)a);
    uint16_t ub = __builtin_bit_cast(uint16_t, (_Float16)b);
    return (uint32_t)ua | ((uint32_t)ub << 16);
}
__device__ __forceinline__ float f16u(uint16_t b) {
    return (float)__builtin_bit_cast(_Float16, b);
}
__device__ __forceinline__ float dot2(uint32_t w, uint32_t h, float acc) {
#if __has_builtin(__builtin_amdgcn_fdot2)
    return __builtin_amdgcn_fdot2(__builtin_bit_cast(half2v, w),
                                  __builtin_bit_cast(half2v, h), acc, false);
#else
    asm("v_fma_mix_f32 %0, %1, %2, %0 op_sel:[0,0,0] op_sel_hi:[1,1,0]"
        : "+v"(acc) : "v"(w), "v"(h));
    asm("v_fma_mix_f32 %0, %1, %2, %0 op_sel:[1,1,0] op_sel_hi:[1,1,0]"
        : "+v"(acc) : "v"(w), "v"(h));
    return acc;
#endif
}

#define DOT4(acc, wv, hv)            \
    acc = dot2(wv.x, hv.x, acc);     \
    acc = dot2(wv.y, hv.y, acc);     \
    acc = dot2(wv.z, hv.z, acc);     \
    acc = dot2(wv.w, hv.w, acc);

__device__ __forceinline__ uint4 pack8(const float* s) {
    uint4 p;
    p.x = pk2(s[0], s[1]); p.y = pk2(s[2], s[3]);
    p.z = pk2(s[4], s[5]); p.w = pk2(s[6], s[7]);
    return p;
}

// Fused 2-layer LSTM encoder (persistent, T=1024) + decoder tail.
// grid = 256 blocks (1/CU), block = 1024 thr (16 waves -> 4 waves/SIMD).
// Thread (s = tid>>8, r = tid&255) owns gate row r's weights IN REGISTERS
// and computes row r for sample s only (96 dot2/step). Update role:
// threads 0..255, (j = tid&63, sq = tid>>6) own unit j of sample sq.
// 3 barriers/step via pre1/pre2 ping-pong.
__global__ __launch_bounds__(1024, 4)
void lstm_fused(const float* __restrict__ x,
                const float* __restrict__ W1i, const float* __restrict__ W1h,
                const float* __restrict__ b1i, const float* __restrict__ b1h,
                const float* __restrict__ W2i, const float* __restrict__ W2h,
                const float* __restrict__ b2i, const float* __restrict__ b2h,
                const float* __restrict__ eW,  const float* __restrict__ eb,
                const float* __restrict__ D1i, const float* __restrict__ D1bi,
                const float* __restrict__ D1bh,
                const float* __restrict__ D2i, const float* __restrict__ D2bi,
                const float* __restrict__ D2bh,
                const float* __restrict__ dW,  const float* __restrict__ db,
                float* __restrict__ out)
{
    __shared__ uint32_t h1L[4][32];  // h1 per sample, f16 pairs
    __shared__ uint32_t h2L[4][32];  // h2 per sample, f16 pairs
    __shared__ float pre1[4][260];   // layer-1 preacts [sample][row] (+pad)
    __shared__ float pre2[4][260];   // layer-2 preacts
    __shared__ float uL[4][8];

    const int tid = threadIdx.x;
    const int blk = blockIdx.x;
    const int s  = tid >> 8;   // this thread's sample
    const int r  = tid & 255;  // gate row
    const int j  = tid & 63;   // update unit
    const int sq = tid >> 6;   // update sample (threads 0..255)

    // ---- pack this row's weights into registers (f16 pairs) ----
    uint4 w1q[8], w2q[8], w3q[8];
    #pragma unroll
    for (int k8 = 0; k8 < 8; ++k8) {
        w1q[k8] = pack8(W1h + r * 64 + k8 * 8);   // Whh1[r,:]
        w2q[k8] = pack8(W2i + r * 64 + k8 * 8);   // Wih2[r,:]
        w3q[k8] = pack8(W2h + r * 64 + k8 * 8);   // Whh2[r,:]
    }
    const float bias1 = b1i[r] + b1h[r];
    const float bias2 = b2i[r] + b2h[r];
    const float wx0 = W1i[r * 3 + 0], wx1 = W1i[r * 3 + 1], wx2 = W1i[r * 3 + 2];

    if (tid < 128) {
        h1L[tid >> 5][tid & 31] = 0u;
        h2L[tid >> 5][tid & 31] = 0u;
    }

    float c1 = 0.0f, c2 = 0.0f;  // state owned by threads 0..255

    const size_t xb = ((size_t)(blk * 4 + s) * 1024) * 3;
    float xa0 = x[xb + 0], xa1 = x[xb + 1], xa2 = x[xb + 2];

    __syncthreads();

    #pragma unroll 1
    for (int t = 0; t < 1024; ++t) {
        // ---- Phase A: layer1 matmul row r, sample s ----
        float a = bias1 + wx0 * xa0 + wx1 * xa1 + wx2 * xa2;
        #pragma unroll
        for (int k8 = 0; k8 < 8; ++k8) {
            const uint4 hv = *(const uint4*)&h1L[s][k8 * 4];
            DOT4(a, w1q[k8], hv)
        }
        pre1[s][r] = a;
        __syncthreads();

        // ---- Phase B: layer1 update (threads 0..255) + x prefetch (all) ----
        int tn = (t < 1023) ? (t + 1) : t;
        const float* q = x + xb + (size_t)tn * 3;
        float xn0 = q[0], xn1 = q[1], xn2 = q[2];
        if (tid < 256) {
            float pi = pre1[sq][j],       pf = pre1[sq][64 + j];
            float pg = pre1[sq][128 + j], po = pre1[sq][192 + j];
            c1 = sigf(pf) * c1 + sigf(pi) * tanhf_fast(pg);
            float hn = sigf(po) * tanhf_fast(c1);
            ((uint16_t*)h1L[sq])[j] = __builtin_bit_cast(uint16_t, (_Float16)hn);
        }
        __syncthreads();

        // ---- Phase C: layer2 matmul (new h1, old h2) ----
        float p = bias2;
        #pragma unroll
        for (int k8 = 0; k8 < 8; ++k8) {
            const uint4 hA = *(const uint4*)&h1L[s][k8 * 4];
            const uint4 hB = *(const uint4*)&h2L[s][k8 * 4];
            DOT4(p, w2q[k8], hA) DOT4(p, w3q[k8], hB)
        }
        pre2[s][r] = p;
        __syncthreads();

        // ---- Phase D: layer2 update (threads 0..255), no trailing barrier ----
        if (tid < 256) {
            float pi = pre2[sq][j],       pf = pre2[sq][64 + j];
            float pg = pre2[sq][128 + j], po = pre2[sq][192 + j];
            c2 = sigf(pf) * c2 + sigf(pi) * tanhf_fast(pg);
            float hn = sigf(po) * tanhf_fast(c2);
            ((uint16_t*)h2L[sq])[j] = __builtin_bit_cast(uint16_t, (_Float16)hn);
        }
        xa0 = xn0; xa1 = xn1; xa2 = xn2;
        // hazards: D writes h2L -> next read of h2L is next C (after 2 barriers);
        // D reads pre2 -> next write of pre2 is next C; next A touches pre1/h1L only.
    }
    __syncthreads();

    // ---- Decoder tail: threads 0..255, wave sq handles sample S ----
    const int S = blk * 4 + sq;

    // u = enc_fc(h2_final)
    if (tid < 256 && j < 5) {
        float acc = eb[j];
        const uint16_t* hh = (const uint16_t*)h2L[sq];
        for (int k = 0; k < 64; ++k) acc += eW[j * 64 + k] * f16u(hh[k]);
        uL[sq][j] = acc;
        out[S * 5 + j] = acc;
    }
    __syncthreads();

    // d1: single step from zero state -> only gates i(0), g(2), o(3) matter
    if (tid < 256) {
        float u0 = uL[sq][0], u1 = uL[sq][1], u2 = uL[sq][2], u3 = uL[sq][3], u4 = uL[sq][4];
        int ri = j, rg = 128 + j, ro = 192 + j;
        float pi = D1bi[ri] + D1bh[ri];
        float pg = D1bi[rg] + D1bh[rg];
        float po = D1bi[ro] + D1bh[ro];
        pi += D1i[ri*5+0]*u0 + D1i[ri*5+1]*u1 + D1i[ri*5+2]*u2 + D1i[ri*5+3]*u3 + D1i[ri*5+4]*u4;
        pg += D1i[rg*5+0]*u0 + D1i[rg*5+1]*u1 + D1i[rg*5+2]*u2 + D1i[rg*5+3]*u3 + D1i[rg*5+4]*u4;
        po += D1i[ro*5+0]*u0 + D1i[ro*5+1]*u1 + D1i[ro*5+2]*u2 + D1i[ro*5+3]*u3 + D1i[ro*5+4]*u4;
        float cd = sigf(pi) * tanhf_fast(pg);
        float hd = sigf(po) * tanhf_fast(cd);
        pre1[sq][j] = hd;
    }
    __syncthreads();

    // d2: single step from zero state
    if (tid < 256) {
        int ri = j, rg = 128 + j, ro = 192 + j;
        float pi = D2bi[ri] + D2bh[ri];
        float pg = D2bi[rg] + D2bh[rg];
        float po = D2bi[ro] + D2bh[ro];
        for (int k = 0; k < 64; ++k) {
            float hk = pre1[sq][k];
            pi += D2i[ri * 64 + k] * hk;
            pg += D2i[rg * 64 + k] * hk;
            po += D2i[ro * 64 + k] * hk;
        }
        float cd = sigf(pi) * tanhf_fast(pg);
        float hd = sigf(po) * tanhf_fast(cd);
        pre1[sq][128 + j] = hd;
    }
    __syncthreads();

    // tau = dec_fc(h_d2)
    if (tid < 256 && j < 3) {
        float acc = db[j];
        for (int k = 0; k < 64; ++k) acc += dW[j * 64 + k] * pre1[sq][128 + k];
        out[5120 + S * 3 + j] = acc;
    }
}

extern "C" void kernel_launch(void* const* d_in, const int* in_sizes, int n_in,
                              void* d_out, int out_size, void* d_ws, size_t ws_size,
                              hipStream_t stream) {
    (void)in_sizes; (void)n_in; (void)out_size; (void)d_ws; (void)ws_size;
    const float* x    = (const float*)d_in[0];
    const float* W1i  = (const float*)d_in[1];
    const float* W1h  = (const float*)d_in[2];
    const float* b1i  = (const float*)d_in[3];
    const float* b1h  = (const float*)d_in[4];
    const float* W2i  = (const float*)d_in[5];
    const float* W2h  = (const float*)d_in[6];
    const float* b2i  = (const float*)d_in[7];
    const float* b2h  = (const float*)d_in[8];
    const float* eW   = (const float*)d_in[9];
    const float* eb   = (const float*)d_in[10];
    const float* D1i  = (const float*)d_in[11];
    const float* D1bi = (const float*)d_in[13];
    const float* D1bh = (const float*)d_in[14];
    const float* D2i  = (const float*)d_in[15];
    const float* D2bi = (const float*)d_in[17];
    const float* D2bh = (const float*)d_in[18];
    const float* dW   = (const float*)d_in[19];
    const float* db   = (const float*)d_in[20];

    hipLaunchKernelGGL(lstm_fused, dim3(256), dim3(1024), 0, stream,
                       x, W1i, W1h, b1i, b1h, W2i, W2h, b2i, b2h, eW, eb,
                       D1i, D1bi, D1bh, D2i, D2bi, D2bh, dW, db,
                       (float*)d_out);
}